// Round 7
// baseline (518.061 us; speedup 1.0000x reference)
//
#include <hip/hip_runtime.h>
#include <cstdint>
#include <cstddef>

// GAT 2-layer (N=8192, D=256), flash softmax with rank-1 scores, f16 MFMA PV.
// Identities:
//   exp(leaky(x)) = max(e^x, e^{a x})
//   p~_ij = adj ? max(Ep_i*F_j, Gp_i*H_j) : 0,  F=e^d, H=e^{a d},
//   Ep = 256*e^{s-m}, Gp = 256*e^{a s-m}   (UNNORMALIZED, x256 for f16-normal)
//   out_i = relu( (P~ @ Wh)_i / rowsum_i ), rowsum_i = sum_j p~_ij
// R23: pv launch_bounds (256,4) -> (256,3). Theory: floors sum to ~150us vs 517
// measured; the ~370us gap must be pv, and the only mechanism of that size is
// VGPR spill -- (256,4) caps the allocator at 128 VGPRs while pv's live set is
// ~120-135 (acc 64 + B 16 + build temps + addresses). (256,3) caps at ~170:
// no spill, 3 blocks/CU (+1/3-round tail is cheap vs per-iter scratch I/O).
// Single change vs R22 for clean A/B attribution.
// ws: bits @8MB (8) | bitsT @16 (8) | small @24 | Bpack @25 (4) | pout @32 (64)

#define ALPHA 0.2f
#define NN 8192
#define DD 256

typedef __attribute__((ext_vector_type(8))) short short8;
typedef __attribute__((ext_vector_type(4))) float f32x4;
typedef __attribute__((ext_vector_type(2))) _Float16 half2v;
typedef __attribute__((ext_vector_type(8))) __fp16 h8;     // builtin ABI type

__device__ __forceinline__ unsigned pk_f16(float a, float b) {
    return __builtin_bit_cast(unsigned, __builtin_amdgcn_cvt_pkrtz(a, b));
}

// sign-extended single-bit extract: 0xFFFFFFFF if bit o of x set, else 0
__device__ __forceinline__ int sbit(uint32_t x, int o) {
    return ((int)(x << (31 - o))) >> 31;
}

__device__ __forceinline__ uint32_t hmerge(uint32_t hi, uint32_t lo) {
#if __has_builtin(__builtin_amdgcn_perm)
    return __builtin_amdgcn_perm(hi, lo, 0x07060100u);   // bytes: lo0,lo1,hi2,hi3
#else
    return (hi & 0xFFFF0000u) | (lo & 0x0000FFFFu);
#endif
}

__device__ __forceinline__ half2v pkmax(half2v a, half2v b) {
#if __has_builtin(__builtin_elementwise_max)
    return __builtin_elementwise_max(a, b);
#else
    half2v r;
    asm("v_pk_max_f16 %0, %1, %2" : "=v"(r) : "v"(a), "v"(b));
    return r;
#endif
}

__device__ __forceinline__ f32x4 mfma_f16(uint4 a, short8 b, f32x4 c) {
    return __builtin_amdgcn_mfma_f32_16x16x32_f16(__builtin_bit_cast(h8, a),
                                                  __builtin_bit_cast(h8, b), c, 0, 0, 0);
}

// ================= device phase bodies =================

// one adjacency row -> 128 u64 mask words; x2 unrolled (8 loads in flight)
__device__ __forceinline__ void packbits_dev(const int* __restrict__ adj,
                                             uint64_t* __restrict__ bits,
                                             int row, int lane) {
    const int* rowp = adj + (size_t)row * NN;
    uint64_t* dst = bits + (size_t)row * 128;
    for (int it = 0; it < 16; it++) {
        const int* p = rowp + it * 512;
        int a0 = p[lane];
        int a1 = p[64 + lane];
        int a2 = p[128 + lane];
        int a3 = p[192 + lane];
        int a4 = p[256 + lane];
        int a5 = p[320 + lane];
        int a6 = p[384 + lane];
        int a7 = p[448 + lane];
        uint64_t m0 = __ballot(a0 != 0);
        uint64_t m1 = __ballot(a1 != 0);
        uint64_t m2 = __ballot(a2 != 0);
        uint64_t m3 = __ballot(a3 != 0);
        uint64_t m4 = __ballot(a4 != 0);
        uint64_t m5 = __ballot(a5 != 0);
        uint64_t m6 = __ballot(a6 != 0);
        uint64_t m7 = __ballot(a7 != 0);
        if (lane == 0) {
            dst[it * 8 + 0] = m0; dst[it * 8 + 1] = m1;
            dst[it * 8 + 2] = m2; dst[it * 8 + 3] = m3;
            dst[it * 8 + 4] = m4; dst[it * 8 + 5] = m5;
            dst[it * 8 + 6] = m6; dst[it * 8 + 7] = m7;
        }
    }
}

// bits [i][w] -> bitsT [w][i], job in [0,512): 64x64 dword tile
__device__ __forceinline__ void transp_dev(const uint32_t* __restrict__ bits32,
                                           uint32_t* __restrict__ bitsT,
                                           int job, unsigned char* smem, int t) {
    uint32_t (*tile)[65] = (uint32_t (*)[65])smem;   // 16640 B
    const int i0 = (job >> 2) * 64;
    const int w0 = (job & 3) * 64;
#pragma unroll
    for (int p = 0; p < 4; p++) {
        int r = (t >> 4) + 16 * p;
        int c4 = (t & 15) * 4;
        uint4 v = *(const uint4*)(bits32 + (size_t)(i0 + r) * 256 + w0 + c4);
        tile[r][c4 + 0] = v.x; tile[r][c4 + 1] = v.y;
        tile[r][c4 + 2] = v.z; tile[r][c4 + 3] = v.w;
    }
    __syncthreads();
#pragma unroll
    for (int p = 0; p < 4; p++) {
        int wr = (t >> 4) + 16 * p;
        int i4 = (t & 15) * 4;
        uint4 o = {tile[i4][wr], tile[i4 + 1][wr], tile[i4 + 2][wr], tile[i4 + 3][wr]};
        *(uint4*)(bitsT + (size_t)(w0 + wr) * NN + i0 + i4) = o;
    }
}

// gemm+rowdots fused: Bpack tile (f16) + per-quarter partial s/dd dots.
// s4/dd4 layout: [cq][row] -- unique writer per (cq,row), no atomics, no zero-init.
__device__ __forceinline__ void gemm_dev(const float* __restrict__ A,
                                         const float* __restrict__ B,
                                         unsigned short* __restrict__ Bpack,
                                         const float* __restrict__ a_src,
                                         const float* __restrict__ a_dst,
                                         float* __restrict__ s4,
                                         float* __restrict__ dd4,
                                         int job, unsigned char* smem, int t) {
    float (*At)[36] = (float (*)[36])smem;                 // 4608 B
    float2 (*Bs)[32] = (float2 (*)[32])(smem + 4608);      // 8192 B
    const int m0 = (job >> 2) * 32;
    const int cq = job & 3;
    const int r0 = (t >> 5) * 4;
    const int cl = t & 31;
    float acc[4][2];
#pragma unroll
    for (int i = 0; i < 4; i++) { acc[i][0] = 0.f; acc[i][1] = 0.f; }

    for (int k0 = 0; k0 < DD; k0 += 32) {
        {
            int row = t >> 3, kq = t & 7;
            float4 v = *(const float4*)(A + (size_t)(m0 + row) * DD + k0 + kq * 4);
            At[kq * 4 + 0][row] = v.x; At[kq * 4 + 1][row] = v.y;
            At[kq * 4 + 2][row] = v.z; At[kq * 4 + 3][row] = v.w;
        }
#pragma unroll
        for (int l2 = 0; l2 < 2; l2++) {
            int fi = l2 * 256 + t;
            int br = fi >> 4, bc4 = fi & 15;      // 32 k-rows x 16 float4 (64 cols)
            float4 v = *(const float4*)(B + (size_t)(k0 + br) * DD + cq * 64 + bc4 * 4);
            Bs[br][bc4 * 2] = {v.x, v.y};
            Bs[br][bc4 * 2 + 1] = {v.z, v.w};
        }
        __syncthreads();
#pragma unroll
        for (int k = 0; k < 32; k++) {
            float4 a0 = *(const float4*)&At[k][r0];
            float2 b = Bs[k][cl];
            float av[4] = {a0.x, a0.y, a0.z, a0.w};
#pragma unroll
            for (int i = 0; i < 4; i++) {
                acc[i][0] += av[i] * b.x;
                acc[i][1] += av[i] * b.y;
            }
        }
        __syncthreads();
    }

    // Bpack epilogue (f16)
    const int jt = m0 >> 5;
    const int lq = ((r0 >> 3) & 3) * 16;
    const int i8 = r0 & 4;
#pragma unroll
    for (int cc = 0; cc < 2; cc++) {
        int c = cq * 64 + cl * 2 + cc;
        int ct = c >> 4;
        int lane = lq + (c & 15);
        uint2 pk;
        pk.x = pk_f16(acc[0][cc], acc[1][cc]);
        pk.y = pk_f16(acc[2][cc], acc[3][cc]);
        *(uint2*)(Bpack + ((size_t)(jt * 16 + ct) * 64 + lane) * 8 + i8) = pk;
    }

    // rowdots epilogue: partial dots over this block's 64 cols -> s4/dd4[cq][row]
    const int c0 = cq * 64 + cl * 2;
    float as0 = a_src[c0], as1 = a_src[c0 + 1];
    float ad0 = a_dst[c0], ad1 = a_dst[c0 + 1];
    float ps[4], pd[4];
#pragma unroll
    for (int i = 0; i < 4; i++) {
        ps[i] = acc[i][0] * as0 + acc[i][1] * as1;
        pd[i] = acc[i][0] * ad0 + acc[i][1] * ad1;
    }
#pragma unroll
    for (int off = 16; off; off >>= 1) {
#pragma unroll
        for (int i = 0; i < 4; i++) {
            ps[i] += __shfl_xor(ps[i], off);
            pd[i] += __shfl_xor(pd[i], off);
        }
    }
    if (cl == 0) {
#pragma unroll
        for (int i = 0; i < 4; i++) {
            s4[(size_t)cq * NN + m0 + r0 + i] = ps[i];
            dd4[(size_t)cq * NN + m0 + r0 + i] = pd[i];
        }
    }
}

// fhgen: sum s4/dd4 partials -> s + FF/HH (packed f16 e^d, e^{a d}) + block dmax.
// job in [0,32), handles rows job*256 .. job*256+255. sred = 4-float LDS scratch.
__device__ __forceinline__ void fhgen_dev(const float* __restrict__ s4,
                                          const float* __restrict__ dd4,
                                          float* __restrict__ s,
                                          uint32_t* __restrict__ FF,
                                          uint32_t* __restrict__ HH,
                                          float* __restrict__ dmax32,
                                          int job, float* sred, int t) {
    const int i = job * 256 + t;
    float ssum = (s4[i] + s4[i + NN]) + (s4[i + 2 * NN] + s4[i + 3 * NN]);
    float dsum = (dd4[i] + dd4[i + NN]) + (dd4[i + 2 * NN] + dd4[i + 3 * NN]);
    s[i] = ssum;
    float F = __expf(dsum);
    float H = __expf(ALPHA * dsum);
    // packed f16 pairs {even j, odd j} for the pv kernel
    float Fn = __shfl_xor(F, 1);
    float Hn = __shfl_xor(H, 1);
    if ((i & 1) == 0) {
        FF[i >> 1] = pk_f16(F, Fn);
        HH[i >> 1] = pk_f16(H, Hn);
    }
    // block max of dsum -> dmax32[job]
    float bm = dsum;
#pragma unroll
    for (int off = 32; off; off >>= 1) bm = fmaxf(bm, __shfl_xor(bm, off));
    const int wave = t >> 6, lane = t & 63;
    if (lane == 0) sred[wave] = bm;
    __syncthreads();
    if (t == 0) dmax32[job] = fmaxf(fmaxf(sred[0], sred[1]), fmaxf(sred[2], sred[3]));
}

// ================= kernels =================

// mega1: gemm(layer1) + packbits interleaved, 3072 blocks.
__global__ __launch_bounds__(256) void mega1(const float* __restrict__ A,
                                             const float* __restrict__ W,
                                             unsigned short* __restrict__ Bpack,
                                             const float* __restrict__ a_src,
                                             const float* __restrict__ a_dst,
                                             float* __restrict__ s4,
                                             float* __restrict__ dd4,
                                             const int* __restrict__ adj,
                                             uint64_t* __restrict__ bits) {
    __shared__ __align__(16) unsigned char smem[12800];
    const int bx = blockIdx.x;
    const int t = threadIdx.x;
    const int sel = bx % 3;
    const int base = bx / 3;
    if (sel == 0) {
        gemm_dev(A, W, Bpack, a_src, a_dst, s4, dd4, base, smem, t);
    } else {
        const int row = base * 8 + (sel - 1) * 4 + (t >> 6);
        packbits_dev(adj, bits, row, t & 63);
    }
}

// megaB: transp (512 blocks) + fhgen (32 blocks) interleaved, layer 1.
__global__ __launch_bounds__(256) void megaB(const uint32_t* __restrict__ bits32,
                                             uint32_t* __restrict__ bitsT,
                                             const float* __restrict__ s4,
                                             const float* __restrict__ dd4,
                                             float* __restrict__ s,
                                             uint32_t* __restrict__ FF,
                                             uint32_t* __restrict__ HH,
                                             float* __restrict__ dmax32) {
    __shared__ __align__(16) unsigned char smem[16640];
    const int bx = blockIdx.x;
    const int t = threadIdx.x;
    if (bx < 512) {
        transp_dev(bits32, bitsT, bx, smem, t);
    } else {
        fhgen_dev(s4, dd4, s, FF, HH, dmax32, bx - 512, (float*)smem, t);
    }
}

// standalone gemm (layer 2) and fhgen (layer 2)
__global__ __launch_bounds__(256) void k_gemm(const float* A, const float* W,
                                              unsigned short* Bpack,
                                              const float* a_src, const float* a_dst,
                                              float* s4, float* dd4) {
    __shared__ __align__(16) unsigned char smem[12800];
    gemm_dev(A, W, Bpack, a_src, a_dst, s4, dd4, blockIdx.x, smem, threadIdx.x);
}
__global__ __launch_bounds__(256) void k_fhgen(const float* __restrict__ s4,
                                               const float* __restrict__ dd4,
                                               float* __restrict__ s,
                                               uint32_t* __restrict__ FF,
                                               uint32_t* __restrict__ HH,
                                               float* __restrict__ dmax32) {
    __shared__ float sred[4];
    fhgen_dev(s4, dd4, s, FF, HH, dmax32, blockIdx.x, sred, threadIdx.x);
}

// epgen: reduce 32 block-maxes -> global dmax; Ep/Gp elementwise. 32 blocks.
__global__ __launch_bounds__(256) void epgen(const float* __restrict__ s,
                                             const float* __restrict__ dmax32,
                                             float* __restrict__ Ep,
                                             float* __restrict__ Gp) {
    __shared__ float sm;
    const int t = threadIdx.x;
    if (t == 0) {
        float m = dmax32[0];
#pragma unroll
        for (int k = 1; k < 32; k++) m = fmaxf(m, dmax32[k]);
        sm = m;
    }
    __syncthreads();
    const float dmax = sm;
    const int i = blockIdx.x * 256 + t;
    float si = s[i];
    float e = si + dmax;
    float m = e >= 0.f ? e : ALPHA * e;
    Ep[i] = 256.0f * __expf(si - m);
    Gp[i] = 256.0f * __expf(ALPHA * si - m);
}

// ---------------- pv v13: v12 with launch_bounds (256,3) ----------------
// (256,4) capped the allocator at 128 VGPRs; pv's live set (acc 64 + B 16 +
// build temps + addresses ~ 120-135) sat at/over the cap -> scratch spills in
// the MFMA loop (the suspected ~10x lump). (256,3) caps ~170: no spill,
// 3 blocks/CU. Everything else identical to v12.
__global__ __launch_bounds__(256, 3) void pv_mfma(const unsigned short* __restrict__ Bpack,
                                                  const uint32_t* __restrict__ bitsT,
                                                  const uint32_t* __restrict__ FF,
                                                  const uint32_t* __restrict__ HH,
                                                  const float* __restrict__ Ep,
                                                  const float* __restrict__ Gp,
                                                  float* __restrict__ pout,
                                                  float* __restrict__ rsum) {
    __shared__ __align__(16) uint4 pb[2][256];      // 8 KB, double-buffered A-frags
    __shared__ __align__(16) uint32_t sFF[512];     // 2 KB, F f16-pairs for this ks
    __shared__ __align__(16) uint32_t sHH[512];     // 2 KB, H f16-pairs for this ks
    const int t = threadIdx.x;
    const int w = t >> 6, l = t & 63;
    const int bx = blockIdx.x;
    const int ks = bx & 7;
    const int i0 = (bx >> 3) * 64;               // block's 64-row base
    const int kbase = ks * 32;                   // 32 chunks per eighth

    const int rl16 = l & 15;
    const int ko = (l >> 4) * 8;                 // k-octet within 32-wide chunk
    const int fo = ko >> 1;                      // word offset within chunk's 16 words
    const int rw = i0 + 16 * w + rl16;           // row this wave builds (f == w)
    const _Float16 eph = (_Float16)Ep[rw];       // already x256, unnormalized
    const _Float16 gph = (_Float16)Gp[rw];
    const half2v ep2 = {eph, eph};
    const half2v gp2 = {gph, gph};

    const unsigned short* bb = Bpack + ((size_t)(w * 4) * 64 + l) * 8;  // cg = w
    const uint32_t* btb = bitsT + rw;            // + cc*NN

    // stage FF/HH ks-slice: 512 words each
    if (t < 128) {
        ((uint4*)sFF)[t] = *(const uint4*)(FF + kbase * 16 + t * 4);
    } else {
        ((uint4*)sHH)[t - 128] = *(const uint4*)(HH + kbase * 16 + (t - 128) * 4);
    }

    f32x4 acc[4][4];
#pragma unroll
    for (int i = 0; i < 4; i++)
#pragma unroll
        for (int q = 0; q < 4; q++) acc[i][q] = (f32x4){0.f, 0.f, 0.f, 0.f};
    float rsv = 0.f;                             // this lane's p~ partial rowsum

    // build the f16 A-frag (4 masked pair-words) for local chunk jl; bw prefetched
    auto build = [&](int jl, uint32_t bw) -> uint4 {
        uint4 fw = *(const uint4*)(sFF + jl * 16 + fo);
        uint4 hw = *(const uint4*)(sHH + jl * 16 + fo);
        const uint32_t fwa[4] = {fw.x, fw.y, fw.z, fw.w};
        const uint32_t hwa[4] = {hw.x, hw.y, hw.z, hw.w};
        const uint32_t wl = bw >> ko;
        uint32_t au[4];
#pragma unroll
        for (int p = 0; p < 4; p++) {
            half2v f2 = __builtin_bit_cast(half2v, fwa[p]);
            half2v h2 = __builtin_bit_cast(half2v, hwa[p]);
            half2v pm = ep2 * f2;
            half2v pa = gp2 * h2;
            half2v px = pkmax(pm, pa);
            uint32_t mlo = (uint32_t)sbit(wl, 2 * p);
            uint32_t mhi = (uint32_t)sbit(wl, 2 * p + 1);
            au[p] = __builtin_bit_cast(uint32_t, px) & hmerge(mhi, mlo);
        }
        // rowsum partial (values <= 256 each, pair-sums <= 2048: f16-safe)
        half2v s01 = __builtin_bit_cast(half2v, au[0]) + __builtin_bit_cast(half2v, au[1]);
        half2v s23 = __builtin_bit_cast(half2v, au[2]) + __builtin_bit_cast(half2v, au[3]);
        half2v sp = s01 + s23;
        rsv += (float)sp.x + (float)sp.y;
        return (uint4){au[0], au[1], au[2], au[3]};
    };

    uint32_t bwc = btb[(size_t)kbase * NN];      // chunk 0 mask word
    __syncthreads();                             // sFF/sHH staged

    uint4 aucur = build(0, bwc);
    pb[0][w * 64 + l] = aucur;
    uint32_t bwn = btb[(size_t)(kbase + 1) * NN];   // prefetch chunk 1

    for (int jl = 0; jl < 32; jl++) {
        const int par = jl & 1;
        const unsigned short* bp = bb + (size_t)(kbase + jl) * 8192;
        short8 B0 = *(const short8*)(bp);        // issued pre-barrier
        short8 B1 = *(const short8*)(bp + 512);
        short8 B2 = *(const short8*)(bp + 1024);
        short8 B3 = *(const short8*)(bp + 1536);

        __syncthreads();   // frag(jl) visible in pb[par]

#pragma unroll
        for (int f = 0; f < 4; f++) {
            uint4 af;
            if (f == w) af = aucur;              // wave-uniform branch
            else        af = pb[par][f * 64 + l];
            acc[f][0] = mfma_f16(af, B0, acc[f][0]);
            acc[f][1] = mfma_f16(af, B1, acc[f][1]);
            acc[f][2] = mfma_f16(af, B2, acc[f][2]);
            acc[f][3] = mfma_f16(af, B3, acc[f][3]);
        }

        if (jl < 31) {
            uint4 an = build(jl + 1, bwn);       // pure VALU + LDS
            pb[par ^ 1][w * 64 + l] = an;
            aucur = an;
            if (jl < 30) bwn = btb[(size_t)(kbase + jl + 2) * NN];   // prefetch
        }
    }

    // finish rowsum: reduce across the 4 k-octet lanes sharing row rw
    rsv += __shfl_xor(rsv, 16);
    rsv += __shfl_xor(rsv, 32);
    if (l < 16) rsum[(size_t)ks * NN + rw] = rsv;

    float* outp = pout + (size_t)ks * NN * DD;
    // C layout: col = l&15, row = (l>>4)*4 + r
#pragma unroll
    for (int f = 0; f < 4; f++) {
        const int orow = i0 + 16 * f + (l >> 4) * 4;
#pragma unroll
        for (int q = 0; q < 4; q++) {
            const int ocol = w * 64 + q * 16 + rl16;
#pragma unroll
            for (int r = 0; r < 4; r++)
                outp[(size_t)(orow + r) * DD + ocol] = acc[f][q][r];
        }
    }
}

// -------- out = relu((sum of 8 partials) / (sum of 8 rowsums)) --------
__global__ __launch_bounds__(256) void combine8(const float* __restrict__ p,
                                                const float* __restrict__ rsum,
                                                float* __restrict__ out) {
    const size_t S = (size_t)NN * DD / 4;   // float4 stride between partials
    size_t idx = (size_t)blockIdx.x * 256 + threadIdx.x;
    const int row = (int)(idx >> 6);        // DD/4 = 64 float4s per row
    float rs = (rsum[row] + rsum[row + NN]) + (rsum[row + 2 * NN] + rsum[row + 3 * NN])
             + (rsum[row + 4 * NN] + rsum[row + 5 * NN])
             + (rsum[row + 6 * NN] + rsum[row + 7 * NN]);
    const float inv = 1.0f / rs;
    float4 a0 = ((const float4*)p)[idx];
    float4 a1 = ((const float4*)p)[idx + S];
    float4 a2 = ((const float4*)p)[idx + 2 * S];
    float4 a3 = ((const float4*)p)[idx + 3 * S];
    float4 a4 = ((const float4*)p)[idx + 4 * S];
    float4 a5 = ((const float4*)p)[idx + 5 * S];
    float4 a6 = ((const float4*)p)[idx + 6 * S];
    float4 a7 = ((const float4*)p)[idx + 7 * S];
    float4 o;
    o.x = fmaxf((((a0.x + a1.x) + (a2.x + a3.x)) + ((a4.x + a5.x) + (a6.x + a7.x))) * inv, 0.f);
    o.y = fmaxf((((a0.y + a1.y) + (a2.y + a3.y)) + ((a4.y + a5.y) + (a6.y + a7.y))) * inv, 0.f);
    o.z = fmaxf((((a0.z + a1.z) + (a2.z + a3.z)) + ((a4.z + a5.z) + (a6.z + a7.z))) * inv, 0.f);
    o.w = fmaxf((((a0.w + a1.w) + (a2.w + a3.w)) + ((a4.w + a5.w) + (a6.w + a7.w))) * inv, 0.f);
    ((float4*)out)[idx] = o;
}

extern "C" void kernel_launch(void* const* d_in, const int* in_sizes, int n_in,
                              void* d_out, int out_size, void* d_ws, size_t ws_size,
                              hipStream_t stream) {
    const float* x   = (const float*)d_in[0];
    const int* adj   = (const int*)d_in[1];
    const float* W1  = (const float*)d_in[2];
    const float* a1s = (const float*)d_in[3];
    const float* a1d = (const float*)d_in[4];
    const float* W2  = (const float*)d_in[5];
    const float* a2s = (const float*)d_in[6];
    const float* a2d = (const float*)d_in[7];
    float* out = (float*)d_out;

    char* ws = (char*)d_ws;
    const size_t MB = 1024ull * 1024ull;
    uint64_t*       bits  = (uint64_t*)(ws + 8 * MB);        // 8 MB
    uint32_t*       bits32= (uint32_t*)bits;
    uint32_t*       bitsT = (uint32_t*)(ws + 16 * MB);       // 8 MB
    float*          sArr  = (float*)(ws + 24 * MB);          // summed s
    float*          EpA   = sArr + NN;
    float*          GpA   = sArr + 2 * NN;
    float*          s4    = sArr + 3 * NN;                   // 4*NN partials
    float*          dd4   = sArr + 7 * NN;                   // 4*NN partials
    float*          rsumA = sArr + 11 * NN;                  // 8*NN rowsum partials
    uint32_t*       FFA   = (uint32_t*)(sArr + 19 * NN);     // NN/2 words (f16 pairs)
    uint32_t*       HHA   = FFA + NN / 2;                    // NN/2 words
    float*          dmax32= sArr + 20 * NN;                  // 32 block maxes
    unsigned short* Bpack = (unsigned short*)(ws + 25 * MB); // 4 MB (f16)
    float*          pout  = (float*)(ws + 32 * MB);          // 64 MB (8 partials)

    // ---------------- Layer 1 (+ shared preprocessing overlapped) ----------------
    mega1<<<dim3(3072), dim3(256), 0, stream>>>(x, W1, Bpack, a1s, a1d, s4, dd4,
                                                adj, bits);
    megaB<<<dim3(544), dim3(256), 0, stream>>>(bits32, bitsT, s4, dd4, sArr,
                                               FFA, HHA, dmax32);
    epgen<<<dim3(32), dim3(256), 0, stream>>>(sArr, dmax32, EpA, GpA);
    pv_mfma<<<dim3(1024), dim3(256), 0, stream>>>(Bpack, bitsT, FFA, HHA, EpA, GpA,
                                                  pout, rsumA);
    combine8<<<dim3(2048), dim3(256), 0, stream>>>(pout, rsumA, out);

    // ---------------- Layer 2 ----------------
    k_gemm<<<dim3(1024), dim3(256), 0, stream>>>(out, W2, Bpack, a2s, a2d, s4, dd4);
    k_fhgen<<<dim3(32), dim3(256), 0, stream>>>(s4, dd4, sArr, FFA, HHA, dmax32);
    epgen<<<dim3(32), dim3(256), 0, stream>>>(sArr, dmax32, EpA, GpA);
    pv_mfma<<<dim3(1024), dim3(256), 0, stream>>>(Bpack, bitsT, FFA, HHA, EpA, GpA,
                                                  pout, rsumA);
    combine8<<<dim3(2048), dim3(256), 0, stream>>>(pout, rsumA, out);
}

// Round 9
// 515.046 us; speedup vs baseline: 1.0059x; 1.0059x over previous
//
#include <hip/hip_runtime.h>
#include <cstdint>
#include <cstddef>

// GAT 2-layer (N=8192, D=256), flash softmax with rank-1 scores, f16 MFMA PV.
// Identities:
//   exp(leaky(x)) = max(e^x, e^{a x})
//   p~_ij = adj ? max(Ep_i*F_j, Gp_i*H_j) : 0,  F=e^d, H=e^{a d},
//   Ep = 256*e^{s-m}, Gp = 256*e^{a s-m}   (UNNORMALIZED, x256 for f16-normal)
//   out_i = relu( (P~ @ Wh)_i / rowsum_i ), rowsum_i = sum_j p~_ij
// R25 = R24 resubmitted (container infra failure, no signal). Changes vs R23:
// (1) epgen launches deleted -- Ep/Gp folded into pv prologue (dmax32 shfl-
// reduce + 2 expf per thread, once per block); (2) partials 8->4 (pv grid 512,
// 64 chunks/block) -- halves pout round-trip (64->32MB per layer); (3) 10->8
// dispatches.
// ws: bits @8MB (8) | bitsT @16 (8) | small @24 | Bpack @25 (4) | pout @32 (32)

#define ALPHA 0.2f
#define NN 8192
#define DD 256

typedef __attribute__((ext_vector_type(8))) short short8;
typedef __attribute__((ext_vector_type(4))) float f32x4;
typedef __attribute__((ext_vector_type(2))) _Float16 half2v;
typedef __attribute__((ext_vector_type(8))) __fp16 h8;     // builtin ABI type

__device__ __forceinline__ unsigned pk_f16(float a, float b) {
    return __builtin_bit_cast(unsigned, __builtin_amdgcn_cvt_pkrtz(a, b));
}

// sign-extended single-bit extract: 0xFFFFFFFF if bit o of x set, else 0
__device__ __forceinline__ int sbit(uint32_t x, int o) {
    return ((int)(x << (31 - o))) >> 31;
}

__device__ __forceinline__ uint32_t hmerge(uint32_t hi, uint32_t lo) {
#if __has_builtin(__builtin_amdgcn_perm)
    return __builtin_amdgcn_perm(hi, lo, 0x07060100u);   // bytes: lo0,lo1,hi2,hi3
#else
    return (hi & 0xFFFF0000u) | (lo & 0x0000FFFFu);
#endif
}

__device__ __forceinline__ half2v pkmax(half2v a, half2v b) {
#if __has_builtin(__builtin_elementwise_max)
    return __builtin_elementwise_max(a, b);
#else
    half2v r;
    asm("v_pk_max_f16 %0, %1, %2" : "=v"(r) : "v"(a), "v"(b));
    return r;
#endif
}

__device__ __forceinline__ f32x4 mfma_f16(uint4 a, short8 b, f32x4 c) {
    return __builtin_amdgcn_mfma_f32_16x16x32_f16(__builtin_bit_cast(h8, a),
                                                  __builtin_bit_cast(h8, b), c, 0, 0, 0);
}

// ================= device phase bodies =================

// one adjacency row -> 128 u64 mask words; x2 unrolled (8 loads in flight)
__device__ __forceinline__ void packbits_dev(const int* __restrict__ adj,
                                             uint64_t* __restrict__ bits,
                                             int row, int lane) {
    const int* rowp = adj + (size_t)row * NN;
    uint64_t* dst = bits + (size_t)row * 128;
    for (int it = 0; it < 16; it++) {
        const int* p = rowp + it * 512;
        int a0 = p[lane];
        int a1 = p[64 + lane];
        int a2 = p[128 + lane];
        int a3 = p[192 + lane];
        int a4 = p[256 + lane];
        int a5 = p[320 + lane];
        int a6 = p[384 + lane];
        int a7 = p[448 + lane];
        uint64_t m0 = __ballot(a0 != 0);
        uint64_t m1 = __ballot(a1 != 0);
        uint64_t m2 = __ballot(a2 != 0);
        uint64_t m3 = __ballot(a3 != 0);
        uint64_t m4 = __ballot(a4 != 0);
        uint64_t m5 = __ballot(a5 != 0);
        uint64_t m6 = __ballot(a6 != 0);
        uint64_t m7 = __ballot(a7 != 0);
        if (lane == 0) {
            dst[it * 8 + 0] = m0; dst[it * 8 + 1] = m1;
            dst[it * 8 + 2] = m2; dst[it * 8 + 3] = m3;
            dst[it * 8 + 4] = m4; dst[it * 8 + 5] = m5;
            dst[it * 8 + 6] = m6; dst[it * 8 + 7] = m7;
        }
    }
}

// bits [i][w] -> bitsT [w][i], job in [0,512): 64x64 dword tile
__device__ __forceinline__ void transp_dev(const uint32_t* __restrict__ bits32,
                                           uint32_t* __restrict__ bitsT,
                                           int job, unsigned char* smem, int t) {
    uint32_t (*tile)[65] = (uint32_t (*)[65])smem;   // 16640 B
    const int i0 = (job >> 2) * 64;
    const int w0 = (job & 3) * 64;
#pragma unroll
    for (int p = 0; p < 4; p++) {
        int r = (t >> 4) + 16 * p;
        int c4 = (t & 15) * 4;
        uint4 v = *(const uint4*)(bits32 + (size_t)(i0 + r) * 256 + w0 + c4);
        tile[r][c4 + 0] = v.x; tile[r][c4 + 1] = v.y;
        tile[r][c4 + 2] = v.z; tile[r][c4 + 3] = v.w;
    }
    __syncthreads();
#pragma unroll
    for (int p = 0; p < 4; p++) {
        int wr = (t >> 4) + 16 * p;
        int i4 = (t & 15) * 4;
        uint4 o = {tile[i4][wr], tile[i4 + 1][wr], tile[i4 + 2][wr], tile[i4 + 3][wr]};
        *(uint4*)(bitsT + (size_t)(w0 + wr) * NN + i0 + i4) = o;
    }
}

// gemm+rowdots fused: Bpack tile (f16) + per-quarter partial s/dd dots.
// s4/dd4 layout: [cq][row] -- unique writer per (cq,row), no atomics, no zero-init.
__device__ __forceinline__ void gemm_dev(const float* __restrict__ A,
                                         const float* __restrict__ B,
                                         unsigned short* __restrict__ Bpack,
                                         const float* __restrict__ a_src,
                                         const float* __restrict__ a_dst,
                                         float* __restrict__ s4,
                                         float* __restrict__ dd4,
                                         int job, unsigned char* smem, int t) {
    float (*At)[36] = (float (*)[36])smem;                 // 4608 B
    float2 (*Bs)[32] = (float2 (*)[32])(smem + 4608);      // 8192 B
    const int m0 = (job >> 2) * 32;
    const int cq = job & 3;
    const int r0 = (t >> 5) * 4;
    const int cl = t & 31;
    float acc[4][2];
#pragma unroll
    for (int i = 0; i < 4; i++) { acc[i][0] = 0.f; acc[i][1] = 0.f; }

    for (int k0 = 0; k0 < DD; k0 += 32) {
        {
            int row = t >> 3, kq = t & 7;
            float4 v = *(const float4*)(A + (size_t)(m0 + row) * DD + k0 + kq * 4);
            At[kq * 4 + 0][row] = v.x; At[kq * 4 + 1][row] = v.y;
            At[kq * 4 + 2][row] = v.z; At[kq * 4 + 3][row] = v.w;
        }
#pragma unroll
        for (int l2 = 0; l2 < 2; l2++) {
            int fi = l2 * 256 + t;
            int br = fi >> 4, bc4 = fi & 15;      // 32 k-rows x 16 float4 (64 cols)
            float4 v = *(const float4*)(B + (size_t)(k0 + br) * DD + cq * 64 + bc4 * 4);
            Bs[br][bc4 * 2] = {v.x, v.y};
            Bs[br][bc4 * 2 + 1] = {v.z, v.w};
        }
        __syncthreads();
#pragma unroll
        for (int k = 0; k < 32; k++) {
            float4 a0 = *(const float4*)&At[k][r0];
            float2 b = Bs[k][cl];
            float av[4] = {a0.x, a0.y, a0.z, a0.w};
#pragma unroll
            for (int i = 0; i < 4; i++) {
                acc[i][0] += av[i] * b.x;
                acc[i][1] += av[i] * b.y;
            }
        }
        __syncthreads();
    }

    // Bpack epilogue (f16)
    const int jt = m0 >> 5;
    const int lq = ((r0 >> 3) & 3) * 16;
    const int i8 = r0 & 4;
#pragma unroll
    for (int cc = 0; cc < 2; cc++) {
        int c = cq * 64 + cl * 2 + cc;
        int ct = c >> 4;
        int lane = lq + (c & 15);
        uint2 pk;
        pk.x = pk_f16(acc[0][cc], acc[1][cc]);
        pk.y = pk_f16(acc[2][cc], acc[3][cc]);
        *(uint2*)(Bpack + ((size_t)(jt * 16 + ct) * 64 + lane) * 8 + i8) = pk;
    }

    // rowdots epilogue: partial dots over this block's 64 cols -> s4/dd4[cq][row]
    const int c0 = cq * 64 + cl * 2;
    float as0 = a_src[c0], as1 = a_src[c0 + 1];
    float ad0 = a_dst[c0], ad1 = a_dst[c0 + 1];
    float ps[4], pd[4];
#pragma unroll
    for (int i = 0; i < 4; i++) {
        ps[i] = acc[i][0] * as0 + acc[i][1] * as1;
        pd[i] = acc[i][0] * ad0 + acc[i][1] * ad1;
    }
#pragma unroll
    for (int off = 16; off; off >>= 1) {
#pragma unroll
        for (int i = 0; i < 4; i++) {
            ps[i] += __shfl_xor(ps[i], off);
            pd[i] += __shfl_xor(pd[i], off);
        }
    }
    if (cl == 0) {
#pragma unroll
        for (int i = 0; i < 4; i++) {
            s4[(size_t)cq * NN + m0 + r0 + i] = ps[i];
            dd4[(size_t)cq * NN + m0 + r0 + i] = pd[i];
        }
    }
}

// fhgen: sum s4/dd4 partials -> s + FF/HH (packed f16 e^d, e^{a d}) + block dmax.
// job in [0,32), handles rows job*256 .. job*256+255. sred = 4-float LDS scratch.
__device__ __forceinline__ void fhgen_dev(const float* __restrict__ s4,
                                          const float* __restrict__ dd4,
                                          float* __restrict__ s,
                                          uint32_t* __restrict__ FF,
                                          uint32_t* __restrict__ HH,
                                          float* __restrict__ dmax32,
                                          int job, float* sred, int t) {
    const int i = job * 256 + t;
    float ssum = (s4[i] + s4[i + NN]) + (s4[i + 2 * NN] + s4[i + 3 * NN]);
    float dsum = (dd4[i] + dd4[i + NN]) + (dd4[i + 2 * NN] + dd4[i + 3 * NN]);
    s[i] = ssum;
    float F = __expf(dsum);
    float H = __expf(ALPHA * dsum);
    // packed f16 pairs {even j, odd j} for the pv kernel
    float Fn = __shfl_xor(F, 1);
    float Hn = __shfl_xor(H, 1);
    if ((i & 1) == 0) {
        FF[i >> 1] = pk_f16(F, Fn);
        HH[i >> 1] = pk_f16(H, Hn);
    }
    // block max of dsum -> dmax32[job]
    float bm = dsum;
#pragma unroll
    for (int off = 32; off; off >>= 1) bm = fmaxf(bm, __shfl_xor(bm, off));
    const int wave = t >> 6, lane = t & 63;
    if (lane == 0) sred[wave] = bm;
    __syncthreads();
    if (t == 0) dmax32[job] = fmaxf(fmaxf(sred[0], sred[1]), fmaxf(sred[2], sred[3]));
}

// ================= kernels =================

// mega1: gemm(layer1) + packbits interleaved, 3072 blocks.
__global__ __launch_bounds__(256) void mega1(const float* __restrict__ A,
                                             const float* __restrict__ W,
                                             unsigned short* __restrict__ Bpack,
                                             const float* __restrict__ a_src,
                                             const float* __restrict__ a_dst,
                                             float* __restrict__ s4,
                                             float* __restrict__ dd4,
                                             const int* __restrict__ adj,
                                             uint64_t* __restrict__ bits) {
    __shared__ __align__(16) unsigned char smem[12800];
    const int bx = blockIdx.x;
    const int t = threadIdx.x;
    const int sel = bx % 3;
    const int base = bx / 3;
    if (sel == 0) {
        gemm_dev(A, W, Bpack, a_src, a_dst, s4, dd4, base, smem, t);
    } else {
        const int row = base * 8 + (sel - 1) * 4 + (t >> 6);
        packbits_dev(adj, bits, row, t & 63);
    }
}

// megaB: transp (512 blocks) + fhgen (32 blocks) interleaved, layer 1.
__global__ __launch_bounds__(256) void megaB(const uint32_t* __restrict__ bits32,
                                             uint32_t* __restrict__ bitsT,
                                             const float* __restrict__ s4,
                                             const float* __restrict__ dd4,
                                             float* __restrict__ s,
                                             uint32_t* __restrict__ FF,
                                             uint32_t* __restrict__ HH,
                                             float* __restrict__ dmax32) {
    __shared__ __align__(16) unsigned char smem[16640];
    const int bx = blockIdx.x;
    const int t = threadIdx.x;
    if (bx < 512) {
        transp_dev(bits32, bitsT, bx, smem, t);
    } else {
        fhgen_dev(s4, dd4, s, FF, HH, dmax32, bx - 512, (float*)smem, t);
    }
}

// standalone gemm (layer 2) and fhgen (layer 2)
__global__ __launch_bounds__(256) void k_gemm(const float* A, const float* W,
                                              unsigned short* Bpack,
                                              const float* a_src, const float* a_dst,
                                              float* s4, float* dd4) {
    __shared__ __align__(16) unsigned char smem[12800];
    gemm_dev(A, W, Bpack, a_src, a_dst, s4, dd4, blockIdx.x, smem, threadIdx.x);
}
__global__ __launch_bounds__(256) void k_fhgen(const float* __restrict__ s4,
                                               const float* __restrict__ dd4,
                                               float* __restrict__ s,
                                               uint32_t* __restrict__ FF,
                                               uint32_t* __restrict__ HH,
                                               float* __restrict__ dmax32) {
    __shared__ float sred[4];
    fhgen_dev(s4, dd4, s, FF, HH, dmax32, blockIdx.x, sred, threadIdx.x);
}

// ---------------- pv v14: 4 partials + inline Ep/Gp (epgen deleted) ----------------
// Grid 512: ks = bx&3 (64 chunks each), row-group = bx>>2. Wave w owns cg=w and
// builds ONLY the f=w A-frag quarter, shared via double-buffered LDS pb
// (contiguous b128, 1 barrier/chunk). FF/HH ks-slice (4KB+4KB) staged to LDS.
// Prologue computes Ep/Gp inline: dmax = shfl-reduce of dmax32[0..31], then
// 2 expf per thread (was the epgen kernel). bitsT word prefetched 1 iter ahead.
// Rowsum accumulated from own p~ fragments; combine4 divides by total.
__global__ __launch_bounds__(256, 4) void pv_mfma(const unsigned short* __restrict__ Bpack,
                                                  const uint32_t* __restrict__ bitsT,
                                                  const uint32_t* __restrict__ FF,
                                                  const uint32_t* __restrict__ HH,
                                                  const float* __restrict__ s,
                                                  const float* __restrict__ dmax32,
                                                  float* __restrict__ pout,
                                                  float* __restrict__ rsum) {
    __shared__ __align__(16) uint4 pb[2][256];      // 8 KB, double-buffered A-frags
    __shared__ __align__(16) uint32_t sFF[1024];    // 4 KB, F f16-pairs for this ks
    __shared__ __align__(16) uint32_t sHH[1024];    // 4 KB, H f16-pairs for this ks
    const int t = threadIdx.x;
    const int w = t >> 6, l = t & 63;
    const int bx = blockIdx.x;
    const int ks = bx & 3;
    const int i0 = (bx >> 2) * 64;               // block's 64-row base
    const int kbase = ks * 64;                   // 64 chunks per quarter

    const int rl16 = l & 15;
    const int ko = (l >> 4) * 8;                 // k-octet within 32-wide chunk
    const int fo = ko >> 1;                      // word offset within chunk's 16 words
    const int rw = i0 + 16 * w + rl16;           // row this wave builds (f == w)

    // inline epgen: global dmax from 32 block-maxes, then Ep/Gp for row rw
    float dm = (l < 32) ? dmax32[l] : -3.0e38f;
#pragma unroll
    for (int off = 32; off; off >>= 1) dm = fmaxf(dm, __shfl_xor(dm, off));
    const float si = s[rw];
    const float e0 = si + dm;
    const float m = e0 >= 0.f ? e0 : ALPHA * e0;
    const float Eps = 256.0f * __expf(si - m);
    const float Gps = 256.0f * __expf(ALPHA * si - m);
    const half2v ep2 = {(_Float16)Eps, (_Float16)Eps};
    const half2v gp2 = {(_Float16)Gps, (_Float16)Gps};

    const unsigned short* bb = Bpack + ((size_t)(w * 4) * 64 + l) * 8;  // cg = w
    const uint32_t* btb = bitsT + rw;            // + cc*NN

    // stage FF/HH ks-slice: 1024 words each (64 chunks x 16 words)
    ((uint4*)sFF)[t] = *(const uint4*)(FF + kbase * 16 + t * 4);
    ((uint4*)sHH)[t] = *(const uint4*)(HH + kbase * 16 + t * 4);

    f32x4 acc[4][4];
#pragma unroll
    for (int i = 0; i < 4; i++)
#pragma unroll
        for (int q = 0; q < 4; q++) acc[i][q] = (f32x4){0.f, 0.f, 0.f, 0.f};
    float rsv = 0.f;                             // this lane's p~ partial rowsum

    // build the f16 A-frag (4 masked pair-words) for local chunk jl; bw prefetched
    auto build = [&](int jl, uint32_t bw) -> uint4 {
        uint4 fw = *(const uint4*)(sFF + jl * 16 + fo);
        uint4 hw = *(const uint4*)(sHH + jl * 16 + fo);
        const uint32_t fwa[4] = {fw.x, fw.y, fw.z, fw.w};
        const uint32_t hwa[4] = {hw.x, hw.y, hw.z, hw.w};
        const uint32_t wl = bw >> ko;
        uint32_t au[4];
#pragma unroll
        for (int p = 0; p < 4; p++) {
            half2v f2 = __builtin_bit_cast(half2v, fwa[p]);
            half2v h2 = __builtin_bit_cast(half2v, hwa[p]);
            half2v pm = ep2 * f2;
            half2v pa = gp2 * h2;
            half2v px = pkmax(pm, pa);
            uint32_t mlo = (uint32_t)sbit(wl, 2 * p);
            uint32_t mhi = (uint32_t)sbit(wl, 2 * p + 1);
            au[p] = __builtin_bit_cast(uint32_t, px) & hmerge(mhi, mlo);
        }
        // rowsum partial (values <= 256 each, pair-sums <= 2048: f16-safe)
        half2v s01 = __builtin_bit_cast(half2v, au[0]) + __builtin_bit_cast(half2v, au[1]);
        half2v s23 = __builtin_bit_cast(half2v, au[2]) + __builtin_bit_cast(half2v, au[3]);
        half2v sp = s01 + s23;
        rsv += (float)sp.x + (float)sp.y;
        return (uint4){au[0], au[1], au[2], au[3]};
    };

    uint32_t bwc = btb[(size_t)kbase * NN];      // chunk 0 mask word
    __syncthreads();                             // sFF/sHH staged

    uint4 aucur = build(0, bwc);
    pb[0][w * 64 + l] = aucur;
    uint32_t bwn = btb[(size_t)(kbase + 1) * NN];   // prefetch chunk 1

    for (int jl = 0; jl < 64; jl++) {
        const int par = jl & 1;
        const unsigned short* bp = bb + (size_t)(kbase + jl) * 8192;
        short8 B0 = *(const short8*)(bp);        // issued pre-barrier
        short8 B1 = *(const short8*)(bp + 512);
        short8 B2 = *(const short8*)(bp + 1024);
        short8 B3 = *(const short8*)(bp + 1536);

        __syncthreads();   // frag(jl) visible in pb[par]

#pragma unroll
        for (int f = 0; f < 4; f++) {
            uint4 af;
            if (f == w) af = aucur;              // wave-uniform branch
            else        af = pb[par][f * 64 + l];
            acc[f][0] = mfma_f16(af, B0, acc[f][0]);
            acc[f][1] = mfma_f16(af, B1, acc[f][1]);
            acc[f][2] = mfma_f16(af, B2, acc[f][2]);
            acc[f][3] = mfma_f16(af, B3, acc[f][3]);
        }

        if (jl < 63) {
            uint4 an = build(jl + 1, bwn);       // pure VALU + LDS
            pb[par ^ 1][w * 64 + l] = an;
            aucur = an;
            if (jl < 62) bwn = btb[(size_t)(kbase + jl + 2) * NN];   // prefetch
        }
    }

    // finish rowsum: reduce across the 4 k-octet lanes sharing row rw
    rsv += __shfl_xor(rsv, 16);
    rsv += __shfl_xor(rsv, 32);
    if (l < 16) rsum[(size_t)ks * NN + rw] = rsv;

    float* outp = pout + (size_t)ks * NN * DD;
    // C layout: col = l&15, row = (l>>4)*4 + r
#pragma unroll
    for (int f = 0; f < 4; f++) {
        const int orow = i0 + 16 * f + (l >> 4) * 4;
#pragma unroll
        for (int q = 0; q < 4; q++) {
            const int ocol = w * 64 + q * 16 + rl16;
#pragma unroll
            for (int r = 0; r < 4; r++)
                outp[(size_t)(orow + r) * DD + ocol] = acc[f][q][r];
        }
    }
}

// -------- out = relu((sum of 4 partials) / (sum of 4 rowsums)) --------
__global__ __launch_bounds__(256) void combine4(const float* __restrict__ p,
                                                const float* __restrict__ rsum,
                                                float* __restrict__ out) {
    const size_t S = (size_t)NN * DD / 4;   // float4 stride between partials
    size_t idx = (size_t)blockIdx.x * 256 + threadIdx.x;
    const int row = (int)(idx >> 6);        // DD/4 = 64 float4s per row
    float rs = (rsum[row] + rsum[row + NN]) + (rsum[row + 2 * NN] + rsum[row + 3 * NN]);
    const float inv = 1.0f / rs;
    float4 a0 = ((const float4*)p)[idx];
    float4 a1 = ((const float4*)p)[idx + S];
    float4 a2 = ((const float4*)p)[idx + 2 * S];
    float4 a3 = ((const float4*)p)[idx + 3 * S];
    float4 o;
    o.x = fmaxf(((a0.x + a1.x) + (a2.x + a3.x)) * inv, 0.f);
    o.y = fmaxf(((a0.y + a1.y) + (a2.y + a3.y)) * inv, 0.f);
    o.z = fmaxf(((a0.z + a1.z) + (a2.z + a3.z)) * inv, 0.f);
    o.w = fmaxf(((a0.w + a1.w) + (a2.w + a3.w)) * inv, 0.f);
    ((float4*)out)[idx] = o;
}

extern "C" void kernel_launch(void* const* d_in, const int* in_sizes, int n_in,
                              void* d_out, int out_size, void* d_ws, size_t ws_size,
                              hipStream_t stream) {
    const float* x   = (const float*)d_in[0];
    const int* adj   = (const int*)d_in[1];
    const float* W1  = (const float*)d_in[2];
    const float* a1s = (const float*)d_in[3];
    const float* a1d = (const float*)d_in[4];
    const float* W2  = (const float*)d_in[5];
    const float* a2s = (const float*)d_in[6];
    const float* a2d = (const float*)d_in[7];
    float* out = (float*)d_out;

    char* ws = (char*)d_ws;
    const size_t MB = 1024ull * 1024ull;
    uint64_t*       bits  = (uint64_t*)(ws + 8 * MB);        // 8 MB
    uint32_t*       bits32= (uint32_t*)bits;
    uint32_t*       bitsT = (uint32_t*)(ws + 16 * MB);       // 8 MB
    float*          sArr  = (float*)(ws + 24 * MB);          // summed s
    float*          s4    = sArr + NN;                       // 4*NN partials
    float*          dd4   = sArr + 5 * NN;                   // 4*NN partials
    float*          rsumA = sArr + 9 * NN;                   // 4*NN rowsum partials
    uint32_t*       FFA   = (uint32_t*)(sArr + 13 * NN);     // NN/2 words (f16 pairs)
    uint32_t*       HHA   = FFA + NN / 2;                    // NN/2 words
    float*          dmax32= sArr + 14 * NN;                  // 32 block maxes
    unsigned short* Bpack = (unsigned short*)(ws + 25 * MB); // 4 MB (f16)
    float*          pout  = (float*)(ws + 32 * MB);          // 32 MB (4 partials)

    // ---------------- Layer 1 (+ shared preprocessing overlapped) ----------------
    mega1<<<dim3(3072), dim3(256), 0, stream>>>(x, W1, Bpack, a1s, a1d, s4, dd4,
                                                adj, bits);
    megaB<<<dim3(544), dim3(256), 0, stream>>>(bits32, bitsT, s4, dd4, sArr,
                                               FFA, HHA, dmax32);
    pv_mfma<<<dim3(512), dim3(256), 0, stream>>>(Bpack, bitsT, FFA, HHA, sArr,
                                                 dmax32, pout, rsumA);
    combine4<<<dim3(2048), dim3(256), 0, stream>>>(pout, rsumA, out);

    // ---------------- Layer 2 ----------------
    k_gemm<<<dim3(1024), dim3(256), 0, stream>>>(out, W2, Bpack, a2s, a2d, s4, dd4);
    k_fhgen<<<dim3(32), dim3(256), 0, stream>>>(s4, dd4, sArr, FFA, HHA, dmax32);
    pv_mfma<<<dim3(512), dim3(256), 0, stream>>>(Bpack, bitsT, FFA, HHA, sArr,
                                                 dmax32, pout, rsumA);
    combine4<<<dim3(2048), dim3(256), 0, stream>>>(pout, rsumA, out);
}